// Round 1
// baseline (243.814 us; speedup 1.0000x reference)
//
#include <hip/hip_runtime.h>

#define B_ROWS 14336
#define D_DIM  512
#define C_CLS  7
#define M_CLS  2048

typedef __attribute__((ext_vector_type(4))) float f32x4;

// fp8 scale: fea*64 -> sigma~3.2 in e4m3 range; Gram scaled by 4096
#define FP8_SCALE 64.0f
#define INV_2S2   (2.0f / 4096.0f)

// K0: fea->fp8 packed in fragment-order image + row norms + logits + zero zb.
// Image layout (direct-load coalesced MFMA fragments): 16B at
// (r16, kp, l) = byte offset ((r16*8 + kp)*64 + l)*16, holding row
// r16*16 + (l&15), bytes {kp*64 + (l>>4)*8 ..+7} (lo) and {+32 ..} (hi).
// A wave's fragment-pair load is one contiguous 1KB global_load_dwordx4.
__global__ __launch_bounds__(256) void k_prep(const float* __restrict__ fea,
                                              const float* __restrict__ W,
                                              char* __restrict__ f8p,
                                              float* __restrict__ an,
                                              float* __restrict__ logits,
                                              float* __restrict__ zb) {  // 64 floats
  int t = threadIdx.x, wave = t >> 6, lane = t & 63;
  if (blockIdx.x == 0 && t < 64) zb[t] = 0.f;
  __shared__ char lrow[16 * 528];  // 16 rows x 512B fp8 (+16 pad)

  int r0 = blockIdx.x * 16;
#pragma unroll
  for (int k = 0; k < 4; ++k) {
    int rl = wave * 4 + k;
    int row = r0 + rl;
    const float4* fr4 = (const float4*)(fea + (size_t)row * D_DIM);
    float4 v0 = fr4[lane * 2], v1 = fr4[lane * 2 + 1];
    float s = v0.x * v0.x + v0.y * v0.y + v0.z * v0.z + v0.w * v0.w +
              v1.x * v1.x + v1.y * v1.y + v1.z * v1.z + v1.w * v1.w;
#pragma unroll
    for (int o = 1; o < 64; o <<= 1) s += __shfl_xor(s, o);
    if (lane == 0) an[row] = s;
    int w0 = __builtin_amdgcn_cvt_pk_fp8_f32(v0.x * FP8_SCALE, v0.y * FP8_SCALE, 0, 0);
    w0     = __builtin_amdgcn_cvt_pk_fp8_f32(v0.z * FP8_SCALE, v0.w * FP8_SCALE, w0, 1);
    int w1 = __builtin_amdgcn_cvt_pk_fp8_f32(v1.x * FP8_SCALE, v1.y * FP8_SCALE, 0, 0);
    w1     = __builtin_amdgcn_cvt_pk_fp8_f32(v1.z * FP8_SCALE, v1.w * FP8_SCALE, w1, 1);
    *(int2*)&lrow[rl * 528 + lane * 8] = make_int2(w0, w1);
#pragma unroll
    for (int c = 0; c < 7; ++c) {
      const float4* w4 = (const float4*)(W + c * D_DIM);
      float4 q0 = w4[lane * 2], q1 = w4[lane * 2 + 1];
      float p = v0.x * q0.x + v0.y * q0.y + v0.z * q0.z + v0.w * q0.w +
                v1.x * q1.x + v1.y * q1.y + v1.z * q1.z + v1.w * q1.w;
#pragma unroll
      for (int o = 1; o < 64; o <<= 1) p += __shfl_xor(p, o);
      if (lane == 0) logits[row * 7 + c] = p;
    }
  }
  __syncthreads();
  // image write-out: 512 16B chunks/block, coalesced
  int4* outp = (int4*)f8p + (size_t)blockIdx.x * 512;
#pragma unroll
  for (int pi = 0; pi < 2; ++pi) {
    int idx = pi * 256 + t;          // [0,512) = (kp, l)
    int kp = idx >> 6, l = idx & 63;
    int sr = l & 15, qk = l >> 4;
    int2 lo = *(const int2*)&lrow[sr * 528 + kp * 64 + qk * 8];
    int2 hi = *(const int2*)&lrow[sr * 528 + kp * 64 + 32 + qk * 8];
    outp[idx] = make_int4(lo.x, lo.y, hi.x, hi.y);
  }
}

// K1: barrier-free, LDS-free Gram + exp reductions. Each WAVE owns one
// independent 64x64 tile (4x4 16x16x32 fp8 frags), loading fragments
// directly global->VGPR from the L2-resident fragment-order image
// (1KB coalesced dwordx4 per frag-pair). No __syncthreads anywhere.
// Grid 2768 = 346 u x 8 xcd, 256 thr (4 waves):
//   xcd<7 : u<132 self class=xcd (528 tri-tiles = 132*4);
//           u in [132,304): cross cbi = xcd*172 + (u-132)
//   xcd==7: u<332 cross cbi = 1204+u; u in [332,346): BN-stat wave jobs
// (xcd7 gets a larger cross share to offset having no self class.)
// Cross pair p = cbi>>8 (256 blocks/pair), <=2 pairs + class0 per XCD.
__global__ __launch_bounds__(256, 4) void k_gram(const char* __restrict__ f8p,
                                                 const float* __restrict__ an,
                                                 const float* __restrict__ logits,
                                                 float* __restrict__ S,
                                                 float* __restrict__ rs_part,
                                                 float* __restrict__ S1,
                                                 float* __restrict__ S2,
                                                 float* __restrict__ aff) {
  int xcd = blockIdx.x & 7, u = blockIdx.x >> 3;
  int t = threadIdx.x, lane = t & 63, wave = t >> 6;
  if (blockIdx.x == 0 && t == 0) aff[0] = 0.f;

  int c1, c2, ti, tj, Sidx;
  bool self;
  if (xcd < 7) {
    if (u < 132) {                       // self triangle, class = xcd
      int job = u * 4 + wave;            // 0..527
      int a = 0, r = job;
      while (r > a) { r -= a + 1; ++a; } // job = a(a+1)/2 + r, r<=a
      ti = a; tj = r;
      c1 = xcd; c2 = xcd; Sidx = xcd; self = true;
    } else if (u < 304) {
      int cbi = xcd * 172 + (u - 132);   // 0..1203
      int p = cbi >> 8;
      int tile = ((cbi & 255) << 2) + wave;
      ti = tile >> 5; tj = tile & 31;
      c1 = p + 1; c2 = 0; Sidx = 7 + p; self = false;
    } else return;
  } else {
    if (u < 332) {
      int cbi = 1204 + u;                // 1204..1535
      int p = cbi >> 8;
      int tile = ((cbi & 255) << 2) + wave;
      ti = tile >> 5; tj = tile & 31;
      c1 = p + 1; c2 = 0; Sidx = 7 + p; self = false;
    } else if (u < 346) {
      // BN stats, wave-level: 56 jobs = (class, 1792-row segment)
      int idx = (u - 332) * 4 + wave;    // 0..55
      int c = idx >> 3, seg = idx & 7;
      int r0 = seg * 1792;
      float s1 = 0.f, s2 = 0.f;
      for (int j = lane; j < 1792; j += 64) {
        float v = logits[(size_t)(r0 + j) * 7 + c];
        s1 += v;
        s2 += v * v;
      }
#pragma unroll
      for (int o = 1; o < 64; o <<= 1) {
        s1 += __shfl_xor(s1, o);
        s2 += __shfl_xor(s2, o);
      }
      if (lane == 0) { atomicAdd(&S1[c], s1); atomicAdd(&S2[c], s2); }
      return;
    } else return;
  }

  int R0 = c1 * M_CLS + ti * 64;
  int C0 = c2 * M_CLS + tj * 64;
  const char* pA = f8p + ((size_t)(R0 >> 4) << 13) + lane * 16;
  const char* pB = f8p + ((size_t)(C0 >> 4) << 13) + lane * 16;

  f32x4 acc[4][4];
#pragma unroll
  for (int i = 0; i < 4; ++i)
#pragma unroll
    for (int j = 0; j < 4; ++j)
      acc[i][j] = (f32x4){0.f, 0.f, 0.f, 0.f};

#pragma unroll
  for (int kp = 0; kp < 8; ++kp) {
    longlong2 fa[4], fb[4];
#pragma unroll
    for (int m = 0; m < 4; ++m) {
      fa[m] = *(const longlong2*)(pA + m * 8192 + kp * 1024);
      fb[m] = *(const longlong2*)(pB + m * 8192 + kp * 1024);
    }
#pragma unroll
    for (int mi = 0; mi < 4; ++mi)
#pragma unroll
      for (int mj = 0; mj < 4; ++mj)
        acc[mi][mj] = __builtin_amdgcn_mfma_f32_16x16x32_fp8_fp8(
            fa[mi].x, fb[mj].x, acc[mi][mj], 0, 0, 0);
#pragma unroll
    for (int mi = 0; mi < 4; ++mi)
#pragma unroll
      for (int mj = 0; mj < 4; ++mj)
        acc[mi][mj] = __builtin_amdgcn_mfma_f32_16x16x32_fp8_fp8(
            fa[mi].y, fb[mj].y, acc[mi][mj], 0, 0, 0);
  }

  // Epilogue. C/D layout (16x16x32): col=lane&15, row=(lane>>4)*4+reg.
  int q = lane >> 4, s = lane & 15;
  f32x4 anA[4];
  float anB[4];
#pragma unroll
  for (int mi = 0; mi < 4; ++mi)
    anA[mi] = *(const f32x4*)&an[R0 + mi * 16 + q * 4];
#pragma unroll
  for (int mj = 0; mj < 4; ++mj)
    anB[mj] = an[C0 + mj * 16 + s];

  bool mirror = self && (ti > tj);
  bool diag = self && (ti == tj);
  float blockAcc = 0.f;
  float colAcc[4] = {0.f, 0.f, 0.f, 0.f};
#pragma unroll
  for (int mi = 0; mi < 4; ++mi) {
#pragma unroll
    for (int rg = 0; rg < 4; ++rg) {
      int rl = mi * 16 + q * 4 + rg;
      float aA = anA[mi][rg];
      float rowAcc = 0.f;
#pragma unroll
      for (int mj = 0; mj < 4; ++mj) {
        int cl = mj * 16 + s;
        float g = acc[mi][mj][rg];
        float d2 = fmaxf(aA + anB[mj] - g * INV_2S2, 0.f);
        if (diag && rl == cl) d2 = 0.f;  // exact diagonal
        float e1 = __expf(-0.05f * d2);
        float e2 = e1 * e1, e4 = e2 * e2, e8 = e4 * e4, e16 = e8 * e8;
        blockAcc += e1 + e2 + e4 + e8 + e16;
        if (self) {
          float ek = __expf(-12.5f * d2);  // KDE: 1/(2*0.2^2)
          rowAcc += ek;
          if (mirror) colAcc[mj] += ek;
        }
      }
      if (self) {
        rowAcc += __shfl_xor(rowAcc, 1);
        rowAcc += __shfl_xor(rowAcc, 2);
        rowAcc += __shfl_xor(rowAcc, 4);
        rowAcc += __shfl_xor(rowAcc, 8);
        if (s == 0) rs_part[(size_t)(R0 + rl) * 32 + tj] = rowAcc;
      }
    }
  }
  if (mirror) {
#pragma unroll
    for (int mj = 0; mj < 4; ++mj) {
      float v = colAcc[mj];
      v += __shfl_xor(v, 16);
      v += __shfl_xor(v, 32);
      if (q == 0)
        rs_part[(size_t)(C0 + mj * 16 + s) * 32 + ti] = v;
    }
    blockAcc *= 2.f;  // mirror tile counted once
  }
#pragma unroll
  for (int o = 1; o < 64; o <<= 1) blockAcc += __shfl_xor(blockAcc, o);
  if (lane == 0) atomicAdd(&S[Sidx], blockAcc);
}

// K2: bnout (blocks 0..391) + per-class KDE weight & affinity term (392..398).
// aff zeroed in k_gram.
__global__ __launch_bounds__(256) void k_final(const float* __restrict__ logits,
                                               const float* __restrict__ S1,
                                               const float* __restrict__ S2,
                                               const float* __restrict__ gamma,
                                               const float* __restrict__ beta,
                                               const float* __restrict__ rs_part,
                                               const float* __restrict__ S,
                                               float* __restrict__ out) {
  int b = blockIdx.x, t = threadIdx.x;
  if (b < 392) {
    int idx = b * 256 + t;  // 392*256 = 100352 exactly
    int row = idx / 7;
    int c = idx - row * 7;
    float mu = S1[c] * (1.f / 14336.f);
    float var = S2[c] * (1.f / 14336.f) - mu * mu;
    out[idx] = gamma[c] * (logits[idx] - mu) * rsqrtf(var + 1e-5f) + beta[c];
    return;
  }
  int c = b - 392;
  // log_norm = -256*ln(2*pi*0.04) - ln(2048)
  const float LOG_NORM = 345.9110632f;
  float v = 0.f;
  for (int i = t; i < M_CLS; i += 256) {
    const float4* rp = (const float4*)(rs_part + (size_t)(c * M_CLS + i) * 32);
    float rsum = 0.f;
#pragma unroll
    for (int jj = 0; jj < 8; ++jj) {
      float4 x = rp[jj];
      rsum += x.x + x.y + x.z + x.w;
    }
    v += 1.f / (logf(rsum) + LOG_NORM);
  }
#pragma unroll
  for (int o = 1; o < 64; o <<= 1) v += __shfl_xor(v, o);
  __shared__ float r[4];
  if ((t & 63) == 0) r[t >> 6] = v;
  __syncthreads();
  if (t == 0) {
    float w = 1.f / ((r[0] + r[1] + r[2] + r[3]) + 1e-5f);
    const float inv_m2 = 1.0f / ((float)M_CLS * (float)M_CLS);
    float Ssrc = S[c];
    float Stgt = (c > 0) ? S[0] : S[1];
    float X    = (c > 0) ? S[6 + c] : S[7];  // cross Sidx 7+p is (p+1,0); X01==X10
    float mmd = (Ssrc + Stgt - 2.f * X) * inv_m2;
    atomicAdd(&out[100352], -mmd * w);
  }
}

extern "C" void kernel_launch(void* const* d_in, const int* in_sizes, int n_in,
                              void* d_out, int out_size, void* d_ws, size_t ws_size,
                              hipStream_t stream) {
  const float* fea   = (const float*)d_in[0];
  const float* W_fc  = (const float*)d_in[1];
  const float* gamma = (const float*)d_in[2];
  const float* beta  = (const float*)d_in[3];
  float* out = (float*)d_out;

  char* ws = (char*)d_ws;
  char* f8p = ws;                                // packed fp8 image: 7,340,032 B
  float* fbase   = (float*)(ws + 7340032);
  float* an      = fbase;                        // 14336
  float* logits  = fbase + 14336;                // 100352
  float* zb      = fbase + 114688;               // 64-float zero block
  float* S1      = zb;                           //   [0..6]
  float* S2      = zb + 7;                       //   [7..13]
  float* S       = zb + 16;                      //   [16..28] (13 used)
  float* rs_part = fbase + 114752;               // 14336*32 row-major (fully written)

  k_prep <<<896,  256, 0, stream>>>(fea, W_fc, f8p, an, logits, zb);
  k_gram <<<2768, 256, 0, stream>>>(f8p, an, logits, S, rs_part, S1, S2,
                                    out + 100352);
  k_final<<<399,  256, 0, stream>>>(logits, S1, S2, gamma, beta, rs_part, S, out);
}

// Round 2
// 241.669 us; speedup vs baseline: 1.0089x; 1.0089x over previous
//
#include <hip/hip_runtime.h>

#define B_ROWS 14336
#define D_DIM  512
#define C_CLS  7
#define M_CLS  2048

typedef __attribute__((ext_vector_type(4))) float f32x4;

// fp8 scale: fea*64 -> sigma~3.2 in e4m3 range; Gram scaled by 4096
#define FP8_SCALE 64.0f
#define INV_2S2   (2.0f / 4096.0f)

// K0: fea->fp8 packed in fragment-order image + row norms + logits + zero zb.
// Image layout (direct-load coalesced MFMA fragments): 16B at
// (r16, kp, l) = byte offset ((r16*8 + kp)*64 + l)*16, holding row
// r16*16 + (l&15), bytes {kp*64 + (l>>4)*8 ..+7} (lo) and {+32 ..} (hi).
// A wave's fragment-pair load is one contiguous 1KB global_load_dwordx4.
__global__ __launch_bounds__(256) void k_prep(const float* __restrict__ fea,
                                              const float* __restrict__ W,
                                              char* __restrict__ f8p,
                                              float* __restrict__ an,
                                              float* __restrict__ logits,
                                              float* __restrict__ zb) {  // 64 floats
  int t = threadIdx.x, wave = t >> 6, lane = t & 63;
  if (blockIdx.x == 0 && t < 64) zb[t] = 0.f;
  __shared__ char lrow[16 * 528];  // 16 rows x 512B fp8 (+16 pad)

  int r0 = blockIdx.x * 16;
#pragma unroll
  for (int k = 0; k < 4; ++k) {
    int rl = wave * 4 + k;
    int row = r0 + rl;
    const float4* fr4 = (const float4*)(fea + (size_t)row * D_DIM);
    float4 v0 = fr4[lane * 2], v1 = fr4[lane * 2 + 1];
    float s = v0.x * v0.x + v0.y * v0.y + v0.z * v0.z + v0.w * v0.w +
              v1.x * v1.x + v1.y * v1.y + v1.z * v1.z + v1.w * v1.w;
#pragma unroll
    for (int o = 1; o < 64; o <<= 1) s += __shfl_xor(s, o);
    if (lane == 0) an[row] = s;
    int w0 = __builtin_amdgcn_cvt_pk_fp8_f32(v0.x * FP8_SCALE, v0.y * FP8_SCALE, 0, 0);
    w0     = __builtin_amdgcn_cvt_pk_fp8_f32(v0.z * FP8_SCALE, v0.w * FP8_SCALE, w0, 1);
    int w1 = __builtin_amdgcn_cvt_pk_fp8_f32(v1.x * FP8_SCALE, v1.y * FP8_SCALE, 0, 0);
    w1     = __builtin_amdgcn_cvt_pk_fp8_f32(v1.z * FP8_SCALE, v1.w * FP8_SCALE, w1, 1);
    *(int2*)&lrow[rl * 528 + lane * 8] = make_int2(w0, w1);
#pragma unroll
    for (int c = 0; c < 7; ++c) {
      const float4* w4 = (const float4*)(W + c * D_DIM);
      float4 q0 = w4[lane * 2], q1 = w4[lane * 2 + 1];
      float p = v0.x * q0.x + v0.y * q0.y + v0.z * q0.z + v0.w * q0.w +
                v1.x * q1.x + v1.y * q1.y + v1.z * q1.z + v1.w * q1.w;
#pragma unroll
      for (int o = 1; o < 64; o <<= 1) p += __shfl_xor(p, o);
      if (lane == 0) logits[row * 7 + c] = p;
    }
  }
  __syncthreads();
  // image write-out: 512 16B chunks/block, coalesced
  int4* outp = (int4*)f8p + (size_t)blockIdx.x * 512;
#pragma unroll
  for (int pi = 0; pi < 2; ++pi) {
    int idx = pi * 256 + t;          // [0,512) = (kp, l)
    int kp = idx >> 6, l = idx & 63;
    int sr = l & 15, qk = l >> 4;
    int2 lo = *(const int2*)&lrow[sr * 528 + kp * 64 + qk * 8];
    int2 hi = *(const int2*)&lrow[sr * 528 + kp * 64 + 32 + qk * 8];
    outp[idx] = make_int4(lo.x, lo.y, hi.x, hi.y);
  }
}

// K1: barrier-free, LDS-free Gram + exp reductions. Each WAVE owns one
// independent 64x64 tile (4x4 16x16x32 fp8 frags), loading fragments
// directly global->VGPR from the L2-resident fragment-order image.
// Explicit 2-buffer software pipeline with STATIC register buffers
// (#pragma unroll 1 on the kp loop so the compiler cannot hoist-and-spill;
// round-1 full unroll spilled ~45MB of scratch -> WRITE_SIZE 47MB).
// Register budget: acc 64 + 2x32 frag + addr ~ 150 < 170 cap from
// __launch_bounds__(256,3) -> zero spill, 12 waves/CU.
// Grid 2768 = 346 u x 8 xcd, 256 thr (4 waves):
//   xcd<7 : u<132 self class=xcd (528 tri-tiles = 132*4);
//           u in [132,304): cross cbi = xcd*172 + (u-132)
//   xcd==7: u<332 cross cbi = 1204+u; u in [332,346): BN-stat wave jobs
__global__ __launch_bounds__(256, 3) void k_gram(const char* __restrict__ f8p,
                                                 const float* __restrict__ an,
                                                 const float* __restrict__ logits,
                                                 float* __restrict__ S,
                                                 float* __restrict__ rs_part,
                                                 float* __restrict__ S1,
                                                 float* __restrict__ S2,
                                                 float* __restrict__ aff) {
  int xcd = blockIdx.x & 7, u = blockIdx.x >> 3;
  int t = threadIdx.x, lane = t & 63, wave = t >> 6;
  if (blockIdx.x == 0 && t == 0) aff[0] = 0.f;

  int c1, c2, ti, tj, Sidx;
  bool self;
  if (xcd < 7) {
    if (u < 132) {                       // self triangle, class = xcd
      int job = u * 4 + wave;            // 0..527
      int a = 0, r = job;
      while (r > a) { r -= a + 1; ++a; } // job = a(a+1)/2 + r, r<=a
      ti = a; tj = r;
      c1 = xcd; c2 = xcd; Sidx = xcd; self = true;
    } else if (u < 304) {
      int cbi = xcd * 172 + (u - 132);   // 0..1203
      int p = cbi >> 8;
      int tile = ((cbi & 255) << 2) + wave;
      ti = tile >> 5; tj = tile & 31;
      c1 = p + 1; c2 = 0; Sidx = 7 + p; self = false;
    } else return;
  } else {
    if (u < 332) {
      int cbi = 1204 + u;                // 1204..1535
      int p = cbi >> 8;
      int tile = ((cbi & 255) << 2) + wave;
      ti = tile >> 5; tj = tile & 31;
      c1 = p + 1; c2 = 0; Sidx = 7 + p; self = false;
    } else if (u < 346) {
      // BN stats, wave-level: 56 jobs = (class, 1792-row segment)
      int idx = (u - 332) * 4 + wave;    // 0..55
      int c = idx >> 3, seg = idx & 7;
      int r0 = seg * 1792;
      float s1 = 0.f, s2 = 0.f;
      for (int j = lane; j < 1792; j += 64) {
        float v = logits[(size_t)(r0 + j) * 7 + c];
        s1 += v;
        s2 += v * v;
      }
#pragma unroll
      for (int o = 1; o < 64; o <<= 1) {
        s1 += __shfl_xor(s1, o);
        s2 += __shfl_xor(s2, o);
      }
      if (lane == 0) { atomicAdd(&S1[c], s1); atomicAdd(&S2[c], s2); }
      return;
    } else return;
  }

  int R0 = c1 * M_CLS + ti * 64;
  int C0 = c2 * M_CLS + tj * 64;
  const char* pA = f8p + ((size_t)(R0 >> 4) << 13) + lane * 16;
  const char* pB = f8p + ((size_t)(C0 >> 4) << 13) + lane * 16;

  f32x4 acc[4][4];
#pragma unroll
  for (int i = 0; i < 4; ++i)
#pragma unroll
    for (int j = 0; j < 4; ++j)
      acc[i][j] = (f32x4){0.f, 0.f, 0.f, 0.f};

#define LOADSET(A_, B_, koff_)                                        \
  do {                                                                \
    _Pragma("unroll")                                                 \
    for (int m_ = 0; m_ < 4; ++m_) {                                  \
      A_[m_] = *(const longlong2*)(pA + m_ * 8192 + (koff_));         \
      B_[m_] = *(const longlong2*)(pB + m_ * 8192 + (koff_));         \
    }                                                                 \
  } while (0)

#define MFMASET(A_, B_)                                               \
  do {                                                                \
    __builtin_amdgcn_s_setprio(1);                                    \
    _Pragma("unroll")                                                 \
    for (int mi_ = 0; mi_ < 4; ++mi_)                                 \
      _Pragma("unroll")                                               \
      for (int mj_ = 0; mj_ < 4; ++mj_)                               \
        acc[mi_][mj_] = __builtin_amdgcn_mfma_f32_16x16x32_fp8_fp8(   \
            A_[mi_].x, B_[mj_].x, acc[mi_][mj_], 0, 0, 0);            \
    _Pragma("unroll")                                                 \
    for (int mi_ = 0; mi_ < 4; ++mi_)                                 \
      _Pragma("unroll")                                               \
      for (int mj_ = 0; mj_ < 4; ++mj_)                               \
        acc[mi_][mj_] = __builtin_amdgcn_mfma_f32_16x16x32_fp8_fp8(   \
            A_[mi_].y, B_[mj_].y, acc[mi_][mj_], 0, 0, 0);            \
    __builtin_amdgcn_s_setprio(0);                                    \
  } while (0)

  {
    longlong2 Ea[4], Eb[4], Oa[4], Ob[4];
    LOADSET(Ea, Eb, 0);
    int koff = 0;
#pragma unroll 1
    for (int it = 0; it < 4; ++it) {
      LOADSET(Oa, Ob, koff + 1024);     // prefetch odd kp
      MFMASET(Ea, Eb);                  // compute even kp
      if (it < 3) LOADSET(Ea, Eb, koff + 2048);  // prefetch next even kp
      MFMASET(Oa, Ob);                  // compute odd kp
      koff += 2048;
    }
  }
#undef LOADSET
#undef MFMASET

  // Epilogue. C/D layout (16x16x32): col=lane&15, row=(lane>>4)*4+reg.
  int q = lane >> 4, s = lane & 15;
  f32x4 anA[4];
  float anB[4];
#pragma unroll
  for (int mi = 0; mi < 4; ++mi)
    anA[mi] = *(const f32x4*)&an[R0 + mi * 16 + q * 4];
#pragma unroll
  for (int mj = 0; mj < 4; ++mj)
    anB[mj] = an[C0 + mj * 16 + s];

  bool mirror = self && (ti > tj);
  bool diag = self && (ti == tj);
  float blockAcc = 0.f;
  float colAcc[4] = {0.f, 0.f, 0.f, 0.f};
#pragma unroll
  for (int mi = 0; mi < 4; ++mi) {
#pragma unroll
    for (int rg = 0; rg < 4; ++rg) {
      int rl = mi * 16 + q * 4 + rg;
      float aA = anA[mi][rg];
      float rowAcc = 0.f;
#pragma unroll
      for (int mj = 0; mj < 4; ++mj) {
        int cl = mj * 16 + s;
        float g = acc[mi][mj][rg];
        float d2 = fmaxf(aA + anB[mj] - g * INV_2S2, 0.f);
        if (diag && rl == cl) d2 = 0.f;  // exact diagonal
        float e1 = __expf(-0.05f * d2);
        float e2 = e1 * e1, e4 = e2 * e2, e8 = e4 * e4, e16 = e8 * e8;
        blockAcc += e1 + e2 + e4 + e8 + e16;
        if (self) {
          float ek = __expf(-12.5f * d2);  // KDE: 1/(2*0.2^2)
          rowAcc += ek;
          if (mirror) colAcc[mj] += ek;
        }
      }
      if (self) {
        rowAcc += __shfl_xor(rowAcc, 1);
        rowAcc += __shfl_xor(rowAcc, 2);
        rowAcc += __shfl_xor(rowAcc, 4);
        rowAcc += __shfl_xor(rowAcc, 8);
        if (s == 0) rs_part[(size_t)(R0 + rl) * 32 + tj] = rowAcc;
      }
    }
  }
  if (mirror) {
#pragma unroll
    for (int mj = 0; mj < 4; ++mj) {
      float v = colAcc[mj];
      v += __shfl_xor(v, 16);
      v += __shfl_xor(v, 32);
      if (q == 0)
        rs_part[(size_t)(C0 + mj * 16 + s) * 32 + ti] = v;
    }
    blockAcc *= 2.f;  // mirror tile counted once
  }
#pragma unroll
  for (int o = 1; o < 64; o <<= 1) blockAcc += __shfl_xor(blockAcc, o);
  if (lane == 0) atomicAdd(&S[Sidx], blockAcc);
}

// K2: bnout (blocks 0..391) + per-class KDE weight & affinity term (392..398).
// aff zeroed in k_gram.
__global__ __launch_bounds__(256) void k_final(const float* __restrict__ logits,
                                               const float* __restrict__ S1,
                                               const float* __restrict__ S2,
                                               const float* __restrict__ gamma,
                                               const float* __restrict__ beta,
                                               const float* __restrict__ rs_part,
                                               const float* __restrict__ S,
                                               float* __restrict__ out) {
  int b = blockIdx.x, t = threadIdx.x;
  if (b < 392) {
    int idx = b * 256 + t;  // 392*256 = 100352 exactly
    int row = idx / 7;
    int c = idx - row * 7;
    float mu = S1[c] * (1.f / 14336.f);
    float var = S2[c] * (1.f / 14336.f) - mu * mu;
    out[idx] = gamma[c] * (logits[idx] - mu) * rsqrtf(var + 1e-5f) + beta[c];
    return;
  }
  int c = b - 392;
  // log_norm = -256*ln(2*pi*0.04) - ln(2048)
  const float LOG_NORM = 345.9110632f;
  float v = 0.f;
  for (int i = t; i < M_CLS; i += 256) {
    const float4* rp = (const float4*)(rs_part + (size_t)(c * M_CLS + i) * 32);
    float rsum = 0.f;
#pragma unroll
    for (int jj = 0; jj < 8; ++jj) {
      float4 x = rp[jj];
      rsum += x.x + x.y + x.z + x.w;
    }
    v += 1.f / (logf(rsum) + LOG_NORM);
  }
#pragma unroll
  for (int o = 1; o < 64; o <<= 1) v += __shfl_xor(v, o);
  __shared__ float r[4];
  if ((t & 63) == 0) r[t >> 6] = v;
  __syncthreads();
  if (t == 0) {
    float w = 1.f / ((r[0] + r[1] + r[2] + r[3]) + 1e-5f);
    const float inv_m2 = 1.0f / ((float)M_CLS * (float)M_CLS);
    float Ssrc = S[c];
    float Stgt = (c > 0) ? S[0] : S[1];
    float X    = (c > 0) ? S[6 + c] : S[7];  // cross Sidx 7+p is (p+1,0); X01==X10
    float mmd = (Ssrc + Stgt - 2.f * X) * inv_m2;
    atomicAdd(&out[100352], -mmd * w);
  }
}

extern "C" void kernel_launch(void* const* d_in, const int* in_sizes, int n_in,
                              void* d_out, int out_size, void* d_ws, size_t ws_size,
                              hipStream_t stream) {
  const float* fea   = (const float*)d_in[0];
  const float* W_fc  = (const float*)d_in[1];
  const float* gamma = (const float*)d_in[2];
  const float* beta  = (const float*)d_in[3];
  float* out = (float*)d_out;

  char* ws = (char*)d_ws;
  char* f8p = ws;                                // packed fp8 image: 7,340,032 B
  float* fbase   = (float*)(ws + 7340032);
  float* an      = fbase;                        // 14336
  float* logits  = fbase + 14336;                // 100352
  float* zb      = fbase + 114688;               // 64-float zero block
  float* S1      = zb;                           //   [0..6]
  float* S2      = zb + 7;                       //   [7..13]
  float* S       = zb + 16;                      //   [16..28] (13 used)
  float* rs_part = fbase + 114752;               // 14336*32 row-major (fully written)

  k_prep <<<896,  256, 0, stream>>>(fea, W_fc, f8p, an, logits, zb);
  k_gram <<<2768, 256, 0, stream>>>(f8p, an, logits, S, rs_part, S1, S2,
                                    out + 100352);
  k_final<<<399,  256, 0, stream>>>(logits, S1, S2, gamma, beta, rs_part, S, out);
}

// Round 3
// 237.908 us; speedup vs baseline: 1.0248x; 1.0158x over previous
//
#include <hip/hip_runtime.h>

#define B_ROWS 14336
#define D_DIM  512
#define C_CLS  7
#define M_CLS  2048

typedef __attribute__((ext_vector_type(4))) float f32x4;

// fp8 scale: fea*64 -> sigma~3.2 in e4m3 range; Gram scaled by 4096
#define FP8_SCALE 64.0f
#define INV_2S2   (2.0f / 4096.0f)

// K0: fea->fp8 packed in fragment-order image + row norms + logits + zero zb.
// Image layout (direct-load coalesced MFMA fragments): 16B at
// (r16, kp, l) = byte offset ((r16*8 + kp)*64 + l)*16, holding row
// r16*16 + (l&15), bytes {kp*64 + (l>>4)*8 ..+7} (lo) and {+32 ..} (hi).
// A wave's fragment-pair load is one contiguous 1KB global_load_dwordx4.
__global__ __launch_bounds__(256) void k_prep(const float* __restrict__ fea,
                                              const float* __restrict__ W,
                                              char* __restrict__ f8p,
                                              float* __restrict__ an,
                                              float* __restrict__ logits,
                                              float* __restrict__ zb) {  // 64 floats
  int t = threadIdx.x, wave = t >> 6, lane = t & 63;
  if (blockIdx.x == 0 && t < 64) zb[t] = 0.f;
  __shared__ char lrow[16 * 528];  // 16 rows x 512B fp8 (+16 pad)

  int r0 = blockIdx.x * 16;
#pragma unroll
  for (int k = 0; k < 4; ++k) {
    int rl = wave * 4 + k;
    int row = r0 + rl;
    const float4* fr4 = (const float4*)(fea + (size_t)row * D_DIM);
    float4 v0 = fr4[lane * 2], v1 = fr4[lane * 2 + 1];
    float s = v0.x * v0.x + v0.y * v0.y + v0.z * v0.z + v0.w * v0.w +
              v1.x * v1.x + v1.y * v1.y + v1.z * v1.z + v1.w * v1.w;
#pragma unroll
    for (int o = 1; o < 64; o <<= 1) s += __shfl_xor(s, o);
    if (lane == 0) an[row] = s;
    int w0 = __builtin_amdgcn_cvt_pk_fp8_f32(v0.x * FP8_SCALE, v0.y * FP8_SCALE, 0, 0);
    w0     = __builtin_amdgcn_cvt_pk_fp8_f32(v0.z * FP8_SCALE, v0.w * FP8_SCALE, w0, 1);
    int w1 = __builtin_amdgcn_cvt_pk_fp8_f32(v1.x * FP8_SCALE, v1.y * FP8_SCALE, 0, 0);
    w1     = __builtin_amdgcn_cvt_pk_fp8_f32(v1.z * FP8_SCALE, v1.w * FP8_SCALE, w1, 1);
    *(int2*)&lrow[rl * 528 + lane * 8] = make_int2(w0, w1);
#pragma unroll
    for (int c = 0; c < 7; ++c) {
      const float4* w4 = (const float4*)(W + c * D_DIM);
      float4 q0 = w4[lane * 2], q1 = w4[lane * 2 + 1];
      float p = v0.x * q0.x + v0.y * q0.y + v0.z * q0.z + v0.w * q0.w +
                v1.x * q1.x + v1.y * q1.y + v1.z * q1.z + v1.w * q1.w;
#pragma unroll
      for (int o = 1; o < 64; o <<= 1) p += __shfl_xor(p, o);
      if (lane == 0) logits[row * 7 + c] = p;
    }
  }
  __syncthreads();
  // image write-out: 512 16B chunks/block, coalesced
  int4* outp = (int4*)f8p + (size_t)blockIdx.x * 512;
#pragma unroll
  for (int pi = 0; pi < 2; ++pi) {
    int idx = pi * 256 + t;          // [0,512) = (kp, l)
    int kp = idx >> 6, l = idx & 63;
    int sr = l & 15, qk = l >> 4;
    int2 lo = *(const int2*)&lrow[sr * 528 + kp * 64 + qk * 8];
    int2 hi = *(const int2*)&lrow[sr * 528 + kp * 64 + 32 + qk * 8];
    outp[idx] = make_int4(lo.x, lo.y, hi.x, hi.y);
  }
}

// K1: barrier-free, LDS-free Gram + exp reductions, 32x32 WAVE tiles.
// Round-2 postmortem: 64x64 tiles need ~148 unified regs -> 1.8-2.4
// waves/SIMD; all pipes <25% busy; latency-bound. 32x32 tiles: acc 16 +
// 2-buffer frags 32 + addr ~ 80 regs -> __launch_bounds__(256,5) (cap 102,
// no spill), 5+ waves/SIMD for 3x latency tolerance; epilogue per wave 4x
// smaller so wave-end serial sections interleave.
// Tile grid per class-pair: 64x64 tiles of 32x32. Jobs are WAVES:
//   self: tri 2080/class x7; cross: 4096 x6; BN: 56.
// Grid 10048 = 1256 u x 8 xcd, 256 thr (4 waves):
//   xcd<7 : u<520 self class=xcd (job = u*4+wave in [0,2080))
//           u in [520,1256): cross cb = xcd*736 + (u-520)   (cb<5152)
//   xcd==7: u<992 cross cb = 5152+u; u in [992,1006): BN waves; else idle
// Cross pair p = cb>>10 (1024 blocks/pair) -> <=2 pairs + class0 per XCD.
// Per-block LDS reduce of blockAcc (all 4 waves share Sidx) keeps tile
// atomics at 1/block.
__global__ __launch_bounds__(256, 5) void k_gram(const char* __restrict__ f8p,
                                                 const float* __restrict__ an,
                                                 const float* __restrict__ logits,
                                                 float* __restrict__ S,
                                                 float* __restrict__ rs_part,
                                                 float* __restrict__ S1,
                                                 float* __restrict__ S2,
                                                 float* __restrict__ aff) {
  int xcd = blockIdx.x & 7, u = blockIdx.x >> 3;
  int t = threadIdx.x, lane = t & 63, wave = t >> 6;
  if (blockIdx.x == 0 && t == 0) aff[0] = 0.f;
  __shared__ float bacc[4];

  int c1, c2, ti, tj, Sidx;
  bool self;
  if (xcd < 7) {
    if (u < 520) {                       // self triangle, class = xcd
      int job = u * 4 + wave;            // 0..2079
      int a = (int)((sqrtf(8.f * (float)job + 1.f) - 1.f) * 0.5f);
      if ((((a + 1) * (a + 2)) >> 1) <= job) ++a;   // fp guards
      if (((a * (a + 1)) >> 1) > job) --a;
      ti = a; tj = job - ((a * (a + 1)) >> 1);
      c1 = xcd; c2 = xcd; Sidx = xcd; self = true;
    } else {
      int cb = xcd * 736 + (u - 520);    // 0..5151
      int p = cb >> 10;
      int tile = ((cb & 1023) << 2) + wave;
      ti = tile >> 6; tj = tile & 63;
      c1 = p + 1; c2 = 0; Sidx = 7 + p; self = false;
    }
  } else {
    if (u < 992) {
      int cb = 5152 + u;                 // 5152..6143
      int p = cb >> 10;
      int tile = ((cb & 1023) << 2) + wave;
      ti = tile >> 6; tj = tile & 63;
      c1 = p + 1; c2 = 0; Sidx = 7 + p; self = false;
    } else if (u < 1006) {
      // BN stats, wave-level: 56 jobs = (class, 1792-row segment)
      int idx = (u - 992) * 4 + wave;    // 0..55
      int c = idx >> 3, seg = idx & 7;
      int r0 = seg * 1792;
      float s1 = 0.f, s2 = 0.f;
      for (int j = lane; j < 1792; j += 64) {
        float v = logits[(size_t)(r0 + j) * 7 + c];
        s1 += v;
        s2 += v * v;
      }
#pragma unroll
      for (int o = 1; o < 64; o <<= 1) {
        s1 += __shfl_xor(s1, o);
        s2 += __shfl_xor(s2, o);
      }
      if (lane == 0) { atomicAdd(&S1[c], s1); atomicAdd(&S2[c], s2); }
      return;
    } else return;
  }

  int R0 = c1 * M_CLS + ti * 32;
  int C0 = c2 * M_CLS + tj * 32;
  const char* pA = f8p + ((size_t)(R0 >> 4) << 13) + lane * 16;
  const char* pB = f8p + ((size_t)(C0 >> 4) << 13) + lane * 16;

  // row norms up-front (tiny, L2-hot; hides under K-loop)
  int q = lane >> 4, s = lane & 15;
  f32x4 anA[2];
  float anB[2];
#pragma unroll
  for (int mi = 0; mi < 2; ++mi)
    anA[mi] = *(const f32x4*)&an[R0 + mi * 16 + q * 4];
#pragma unroll
  for (int mj = 0; mj < 2; ++mj)
    anB[mj] = an[C0 + mj * 16 + s];

  f32x4 acc[2][2];
#pragma unroll
  for (int i = 0; i < 2; ++i)
#pragma unroll
    for (int j = 0; j < 2; ++j)
      acc[i][j] = (f32x4){0.f, 0.f, 0.f, 0.f};

#define LOADSET(A_, B_, koff_)                                        \
  do {                                                                \
    _Pragma("unroll")                                                 \
    for (int m_ = 0; m_ < 2; ++m_) {                                  \
      A_[m_] = *(const longlong2*)(pA + m_ * 8192 + (koff_));         \
      B_[m_] = *(const longlong2*)(pB + m_ * 8192 + (koff_));         \
    }                                                                 \
  } while (0)

#define MFMASET(A_, B_)                                               \
  do {                                                                \
    __builtin_amdgcn_s_setprio(1);                                    \
    _Pragma("unroll")                                                 \
    for (int mi_ = 0; mi_ < 2; ++mi_)                                 \
      _Pragma("unroll")                                               \
      for (int mj_ = 0; mj_ < 2; ++mj_)                               \
        acc[mi_][mj_] = __builtin_amdgcn_mfma_f32_16x16x32_fp8_fp8(   \
            A_[mi_].x, B_[mj_].x, acc[mi_][mj_], 0, 0, 0);            \
    _Pragma("unroll")                                                 \
    for (int mi_ = 0; mi_ < 2; ++mi_)                                 \
      _Pragma("unroll")                                               \
      for (int mj_ = 0; mj_ < 2; ++mj_)                               \
        acc[mi_][mj_] = __builtin_amdgcn_mfma_f32_16x16x32_fp8_fp8(   \
            A_[mi_].y, B_[mj_].y, acc[mi_][mj_], 0, 0, 0);            \
    __builtin_amdgcn_s_setprio(0);                                    \
  } while (0)

  {
    longlong2 Ea[2], Eb[2], Oa[2], Ob[2];
    LOADSET(Ea, Eb, 0);
    int koff = 0;
#pragma unroll 1
    for (int it = 0; it < 4; ++it) {
      LOADSET(Oa, Ob, koff + 1024);     // prefetch odd kp
      MFMASET(Ea, Eb);                  // compute even kp
      if (it < 3) LOADSET(Ea, Eb, koff + 2048);  // prefetch next even kp
      MFMASET(Oa, Ob);                  // compute odd kp
      koff += 2048;
    }
  }
#undef LOADSET
#undef MFMASET

  // Epilogue. C/D layout (16x16x32): col=lane&15, row=(lane>>4)*4+reg.
  bool mirror = self && (ti > tj);
  bool diag = self && (ti == tj);
  float blockAcc = 0.f;
  float colAcc[2] = {0.f, 0.f};
#pragma unroll
  for (int mi = 0; mi < 2; ++mi) {
#pragma unroll
    for (int rg = 0; rg < 4; ++rg) {
      int rl = mi * 16 + q * 4 + rg;
      float aA = anA[mi][rg];
      float rowAcc = 0.f;
#pragma unroll
      for (int mj = 0; mj < 2; ++mj) {
        int cl = mj * 16 + s;
        float g = acc[mi][mj][rg];
        float d2 = fmaxf(aA + anB[mj] - g * INV_2S2, 0.f);
        if (diag && rl == cl) d2 = 0.f;  // exact diagonal
        float e1 = __expf(-0.05f * d2);
        float e2 = e1 * e1, e4 = e2 * e2, e8 = e4 * e4, e16 = e8 * e8;
        blockAcc += e1 + e2 + e4 + e8 + e16;
        if (self) {
          float ek = __expf(-12.5f * d2);  // KDE: 1/(2*0.2^2)
          rowAcc += ek;
          if (mirror) colAcc[mj] += ek;
        }
      }
      if (self) {
        rowAcc += __shfl_xor(rowAcc, 1);
        rowAcc += __shfl_xor(rowAcc, 2);
        rowAcc += __shfl_xor(rowAcc, 4);
        rowAcc += __shfl_xor(rowAcc, 8);
        if (s == 0) rs_part[(size_t)(R0 + rl) * 64 + tj] = rowAcc;
      }
    }
  }
  if (mirror) {
#pragma unroll
    for (int mj = 0; mj < 2; ++mj) {
      float v = colAcc[mj];
      v += __shfl_xor(v, 16);
      v += __shfl_xor(v, 32);
      if (q == 0)
        rs_part[(size_t)(C0 + mj * 16 + s) * 64 + ti] = v;
    }
    blockAcc *= 2.f;  // mirror tile counted once
  }
#pragma unroll
  for (int o = 1; o < 64; o <<= 1) blockAcc += __shfl_xor(blockAcc, o);
  // block-level reduce: all 4 waves of a gram block share Sidx
  if (lane == 0) bacc[wave] = blockAcc;
  __syncthreads();
  if (t == 0) atomicAdd(&S[Sidx], bacc[0] + bacc[1] + bacc[2] + bacc[3]);
}

// K2: bnout (blocks 0..391) + per-class KDE weight & affinity term (392..398).
// aff zeroed in k_gram.
__global__ __launch_bounds__(256) void k_final(const float* __restrict__ logits,
                                               const float* __restrict__ S1,
                                               const float* __restrict__ S2,
                                               const float* __restrict__ gamma,
                                               const float* __restrict__ beta,
                                               const float* __restrict__ rs_part,
                                               const float* __restrict__ S,
                                               float* __restrict__ out) {
  int b = blockIdx.x, t = threadIdx.x;
  if (b < 392) {
    int idx = b * 256 + t;  // 392*256 = 100352 exactly
    int row = idx / 7;
    int c = idx - row * 7;
    float mu = S1[c] * (1.f / 14336.f);
    float var = S2[c] * (1.f / 14336.f) - mu * mu;
    out[idx] = gamma[c] * (logits[idx] - mu) * rsqrtf(var + 1e-5f) + beta[c];
    return;
  }
  int c = b - 392;
  // log_norm = -256*ln(2*pi*0.04) - ln(2048)
  const float LOG_NORM = 345.9110632f;
  float v = 0.f;
  for (int i = t; i < M_CLS; i += 256) {
    const float4* rp = (const float4*)(rs_part + (size_t)(c * M_CLS + i) * 64);
    float rsum = 0.f;
#pragma unroll
    for (int jj = 0; jj < 16; ++jj) {
      float4 x = rp[jj];
      rsum += x.x + x.y + x.z + x.w;
    }
    v += 1.f / (logf(rsum) + LOG_NORM);
  }
#pragma unroll
  for (int o = 1; o < 64; o <<= 1) v += __shfl_xor(v, o);
  __shared__ float r[4];
  if ((t & 63) == 0) r[t >> 6] = v;
  __syncthreads();
  if (t == 0) {
    float w = 1.f / ((r[0] + r[1] + r[2] + r[3]) + 1e-5f);
    const float inv_m2 = 1.0f / ((float)M_CLS * (float)M_CLS);
    float Ssrc = S[c];
    float Stgt = (c > 0) ? S[0] : S[1];
    float X    = (c > 0) ? S[6 + c] : S[7];  // cross Sidx 7+p is (p+1,0); X01==X10
    float mmd = (Ssrc + Stgt - 2.f * X) * inv_m2;
    atomicAdd(&out[100352], -mmd * w);
  }
}

extern "C" void kernel_launch(void* const* d_in, const int* in_sizes, int n_in,
                              void* d_out, int out_size, void* d_ws, size_t ws_size,
                              hipStream_t stream) {
  const float* fea   = (const float*)d_in[0];
  const float* W_fc  = (const float*)d_in[1];
  const float* gamma = (const float*)d_in[2];
  const float* beta  = (const float*)d_in[3];
  float* out = (float*)d_out;

  char* ws = (char*)d_ws;
  char* f8p = ws;                                // packed fp8 image: 7,340,032 B
  float* fbase   = (float*)(ws + 7340032);
  float* an      = fbase;                        // 14336
  float* logits  = fbase + 14336;                // 100352
  float* zb      = fbase + 114688;               // 64-float zero block
  float* S1      = zb;                           //   [0..6]
  float* S2      = zb + 7;                       //   [7..13]
  float* S       = zb + 16;                      //   [16..28] (13 used)
  float* rs_part = fbase + 114752;               // 14336*64 row-major (fully written)

  k_prep <<<896,   256, 0, stream>>>(fea, W_fc, f8p, an, logits, zb);
  k_gram <<<10048, 256, 0, stream>>>(f8p, an, logits, S, rs_part, S1, S2,
                                     out + 100352);
  k_final<<<399,   256, 0, stream>>>(logits, S1, S2, gamma, beta, rs_part, S, out);
}